// Round 1
// baseline (986.982 us; speedup 1.0000x reference)
//
#include <hip/hip_runtime.h>
#include <math.h>

// Problem constants (from reference)
#define Bn   2
#define Ln   1024
#define DIMn 256
#define DIn  512
#define DSn  64
#define DTRn 16
#define Kn   4
#define HIDn 1024

__device__ __forceinline__ float silu_f(float x) { return x / (1.f + __expf(-x)); }
__device__ __forceinline__ float softplus_f(float x) { return (x > 20.f) ? x : log1pf(__expf(x)); }
__device__ __forceinline__ float gelu_f(float x) {
    float x3 = x * x * x;
    float t = tanhf(0.7978845608028654f * (x + 0.044715f * x3));
    return 0.5f * x * (1.f + t);
}
// scan-direction index permutation: xs[b,k,l,:] = xic[b, permidx(k,l), :]
__device__ __forceinline__ int permidx(int k, int l) {
    switch (k & 3) {
        case 0:  return l;
        case 1:  return ((l & 31) << 5) | (l >> 5);
        case 2:  return (Ln - 1) - l;
        default: { int j = (Ln - 1) - l; return ((j & 31) << 5) | (j >> 5); }
    }
}

// ---------------------------------------------------------------- k_mod
// mod[b, 0:1536] = silu(c[b]) @ W_ada + b_ada
__global__ __launch_bounds__(256) void k_mod(const float* __restrict__ c,
                                             const float* __restrict__ W,
                                             const float* __restrict__ bias,
                                             float* __restrict__ mod) {
    __shared__ float sc[DIMn];
    int b = blockIdx.y;
    int j = blockIdx.x * 256 + threadIdx.x;
    sc[threadIdx.x] = silu_f(c[b * DIMn + threadIdx.x]);
    __syncthreads();
    float acc = bias[j];
#pragma unroll 4
    for (int r = 0; r < DIMn; r++) acc = fmaf(sc[r], W[r * 1536 + j], acc);
    mod[b * 1536 + j] = acc;
}

// ---------------------------------------------------------------- k_ln_mod
// out[b,l,:] = LN(in[b,l,:]) * (1 + mod[b, sc_ofs:+256]) + mod[b, sh_ofs:+256]
__global__ __launch_bounds__(256) void k_ln_mod(const float* __restrict__ x,
                                                const float* __restrict__ mod,
                                                int sh_ofs, int sc_ofs,
                                                float* __restrict__ out) {
    int b = blockIdx.y, l = blockIdx.x, d = threadIdx.x;
    float v = x[((size_t)(b << 10) + l) * DIMn + d];
    float s1 = v, s2 = v * v;
#pragma unroll
    for (int o = 32; o > 0; o >>= 1) { s1 += __shfl_xor(s1, o); s2 += __shfl_xor(s2, o); }
    __shared__ float red[8];
    int wid = threadIdx.x >> 6, lane = threadIdx.x & 63;
    if (lane == 0) { red[wid * 2] = s1; red[wid * 2 + 1] = s2; }
    __syncthreads();
    s1 = red[0] + red[2] + red[4] + red[6];
    s2 = red[1] + red[3] + red[5] + red[7];
    float mu  = s1 * (1.f / DIMn);
    float var = s2 * (1.f / DIMn) - mu * mu;
    float r   = rsqrtf(var + 1e-6f);
    float sh  = mod[b * 1536 + sh_ofs + d];
    float scv = mod[b * 1536 + sc_ofs + d];
    out[((size_t)(b << 10) + l) * DIMn + d] = (v - mu) * r * (1.f + scv) + sh;
}

// ---------------------------------------------------------------- gemm64
// C[M,N] = A[M,Kd] @ W[Kd,N]; 64x64 tile, 16x16 threads, 4x4 micro-tile.
// EPI 0: +bias   EPI 1: gelu(+bias)   EPI 2: resid + mod[b,gofs+n]*(+bias)
template <int EPI>
__global__ __launch_bounds__(256) void gemm64(const float* __restrict__ A,
                                              const float* __restrict__ W,
                                              const float* __restrict__ bias,
                                              float* __restrict__ out,
                                              int N, int Kd,
                                              const float* __restrict__ resid,
                                              const float* __restrict__ mod,
                                              int gofs) {
    __shared__ float As[16][68];
    __shared__ float Bs[16][68];
    int row0 = blockIdx.y << 6, col0 = blockIdx.x << 6;
    int tx = threadIdx.x & 15, ty = threadIdx.x >> 4;
    float acc[4][4] = {};
    for (int k0 = 0; k0 < Kd; k0 += 16) {
#pragma unroll
        for (int i = 0; i < 4; i++) {
            int idx = threadIdx.x + i * 256;
            int m = idx >> 4, kk = idx & 15;
            As[kk][m] = A[(size_t)(row0 + m) * Kd + k0 + kk];
            int n = idx & 63, k2 = idx >> 6;
            int col = col0 + n;
            Bs[k2][n] = (col < N) ? W[(size_t)(k0 + k2) * N + col] : 0.f;
        }
        __syncthreads();
#pragma unroll
        for (int kk = 0; kk < 16; kk++) {
            float a[4], bb[4];
#pragma unroll
            for (int i = 0; i < 4; i++) a[i] = As[kk][ty * 4 + i];
#pragma unroll
            for (int j = 0; j < 4; j++) bb[j] = Bs[kk][tx * 4 + j];
#pragma unroll
            for (int i = 0; i < 4; i++)
#pragma unroll
                for (int j = 0; j < 4; j++) acc[i][j] = fmaf(a[i], bb[j], acc[i][j]);
        }
        __syncthreads();
    }
#pragma unroll
    for (int i = 0; i < 4; i++) {
        int row = row0 + ty * 4 + i;
#pragma unroll
        for (int j = 0; j < 4; j++) {
            int col = col0 + tx * 4 + j;
            if (col < N) {
                float v = acc[i][j] + bias[col];
                if (EPI == 1) v = gelu_f(v);
                if (EPI == 2) v = resid[(size_t)row * N + col] +
                                  mod[(row >> 10) * 1536 + gofs + col] * v;
                out[(size_t)row * N + col] = v;
            }
        }
    }
}

// ---------------------------------------------------------------- gemm_xdbl
// xdbl[b,k,l,0:144] = xic[b, permidx(k,l), :] @ W_xproj[k]   (Kd=512, N=144)
__global__ __launch_bounds__(256) void gemm_xdbl(const float* __restrict__ xic,
                                                 const float* __restrict__ Wx,
                                                 float* __restrict__ xdbl) {
    __shared__ float As[16][68];
    __shared__ float Bs[16][68];
    int bk = blockIdx.z;              // b*4+k
    int b = bk >> 2, k = bk & 3;
    int row0 = blockIdx.y << 6, col0 = blockIdx.x << 6;
    const float* Ab = xic + (size_t)b * Ln * DIn;
    const float* Wb = Wx + (size_t)k * DIn * 144;
    float* ob = xdbl + (size_t)bk * Ln * 144;
    int tx = threadIdx.x & 15, ty = threadIdx.x >> 4;
    float acc[4][4] = {};
    for (int k0 = 0; k0 < DIn; k0 += 16) {
#pragma unroll
        for (int i = 0; i < 4; i++) {
            int idx = threadIdx.x + i * 256;
            int m = idx >> 4, kk = idx & 15;
            As[kk][m] = Ab[(size_t)permidx(k, row0 + m) * DIn + k0 + kk];
            int n = idx & 63, k2 = idx >> 6;
            int col = col0 + n;
            Bs[k2][n] = (col < 144) ? Wb[(size_t)(k0 + k2) * 144 + col] : 0.f;
        }
        __syncthreads();
#pragma unroll
        for (int kk = 0; kk < 16; kk++) {
            float a[4], bb[4];
#pragma unroll
            for (int i = 0; i < 4; i++) a[i] = As[kk][ty * 4 + i];
#pragma unroll
            for (int j = 0; j < 4; j++) bb[j] = Bs[kk][tx * 4 + j];
#pragma unroll
            for (int i = 0; i < 4; i++)
#pragma unroll
                for (int j = 0; j < 4; j++) acc[i][j] = fmaf(a[i], bb[j], acc[i][j]);
        }
        __syncthreads();
    }
#pragma unroll
    for (int i = 0; i < 4; i++) {
        int row = row0 + ty * 4 + i;
#pragma unroll
        for (int j = 0; j < 4; j++) {
            int col = col0 + tx * 4 + j;
            if (col < 144) ob[(size_t)row * 144 + col] = acc[i][j];
        }
    }
}

// ---------------------------------------------------------------- k_conv
// depthwise 3x3 SAME + bias + silu on xi = xz[..., :512]
__global__ __launch_bounds__(256) void k_conv(const float* __restrict__ xz,
                                              const float* __restrict__ cw,
                                              const float* __restrict__ cb,
                                              float* __restrict__ xic) {
    int idx = blockIdx.x * 256 + threadIdx.x;   // b*L*512 + l*512 + d
    int d = idx & 511;
    int l = (idx >> 9) & 1023;
    int b = idx >> 19;
    int hh = l >> 5, ww = l & 31;
    float acc = cb[d];
#pragma unroll
    for (int ky = 0; ky < 3; ky++) {
        int y = hh + ky - 1;
        if ((unsigned)y >= 32u) continue;
#pragma unroll
        for (int kx = 0; kx < 3; kx++) {
            int xw = ww + kx - 1;
            if ((unsigned)xw >= 32u) continue;
            acc = fmaf(cw[(ky * 3 + kx) * DIn + d],
                       xz[((size_t)(b << 10) + (y << 5) + xw) * 1024 + d], acc);
        }
    }
    xic[idx] = silu_f(acc);
}

// ---------------------------------------------------------------- k_dt
// dtt[b,k,d,l] = softplus(xdbl[b,k,l,0:16] @ W_dt[k] + dt_bias[k,d]) — transposed store
__global__ __launch_bounds__(256) void k_dt(const float* __restrict__ xdbl,
                                            const float* __restrict__ W_dt,
                                            const float* __restrict__ dt_bias,
                                            float* __restrict__ dtt) {
    __shared__ float Wd[16][64];
    __shared__ float Ar[64][16];
    __shared__ float tile[64][65];
    int bk = blockIdx.z;   // b*4+k
    int k = bk & 3;
    int l0 = blockIdx.x << 6, d0 = blockIdx.y << 6;
    const float* xb = xdbl + (size_t)bk * Ln * 144;
#pragma unroll
    for (int i = 0; i < 4; i++) {
        int idx = threadIdx.x + i * 256;
        int r = idx >> 6, dl = idx & 63;
        Wd[r][dl] = W_dt[(size_t)(k * 16 + r) * DIn + d0 + dl];
        int lr = idx >> 4, r2 = idx & 15;
        Ar[lr][r2] = xb[(size_t)(l0 + lr) * 144 + r2];
    }
    __syncthreads();
    {
        int dl = threadIdx.x & 63, lb = threadIdx.x >> 6;
        float bias = dt_bias[k * DIn + d0 + dl];
#pragma unroll
        for (int i = 0; i < 16; i++) {
            int lr = lb * 16 + i;
            float acc = bias;
#pragma unroll
            for (int r = 0; r < 16; r++) acc = fmaf(Ar[lr][r], Wd[r][dl], acc);
            tile[lr][dl] = softplus_f(acc);
        }
    }
    __syncthreads();
    {
        int ll = threadIdx.x & 63, db = threadIdx.x >> 6;
        float* ob = dtt + ((size_t)bk * DIn + d0) * Ln + l0;
#pragma unroll
        for (int i = 0; i < 16; i++) {
            int dl2 = db * 16 + i;
            ob[(size_t)dl2 * Ln + ll] = tile[ll][dl2];
        }
    }
}

// ---------------------------------------------------------------- k_scan
// One wave per (b,k,d); lanes = 64 states. ys[b,k,d,l] = y_l + u_l*Dp  (coalesced)
__global__ __launch_bounds__(256) void k_scan(const float* __restrict__ dtt,
                                              const float* __restrict__ xdbl,
                                              const float* __restrict__ xic,
                                              const float* __restrict__ A_log,
                                              const float* __restrict__ Dp,
                                              float* __restrict__ ys) {
    int wid = threadIdx.x >> 6, lane = threadIdx.x & 63;
    int g = blockIdx.x * 4 + wid;          // (b*4+k)*512 + d
    int d = g & 511;
    int bk = g >> 9;
    int k = bk & 3;
    const float* dtp = dtt + (size_t)g * Ln;
    const float* xdb = xdbl + (size_t)bk * Ln * 144;
    const float* xcb = xic + (size_t)(bk >> 2) * Ln * DIn + d;
    float* ysp = ys + (size_t)g * Ln;
    float Aln = -__expf(A_log[(size_t)(k * DIn + d) * DSn + lane]);
    float Dv  = Dp[k * DIn + d];
    float h = 0.f, yreg = 0.f;
    for (int l0 = 0; l0 < Ln; l0 += 64) {
#pragma unroll 8
        for (int j = 0; j < 64; j++) {
            int l = l0 + j;
            float dt = dtp[l];
            float u  = xcb[(size_t)permidx(k, l) * DIn];
            float Bv = xdb[l * 144 + 16 + lane];
            float Cv = xdb[l * 144 + 80 + lane];
            float dA = __expf(dt * Aln);
            h = fmaf(h, dA, (dt * u) * Bv);
            float p = h * Cv;
#pragma unroll
            for (int o = 32; o > 0; o >>= 1) p += __shfl_xor(p, o);
            p = fmaf(u, Dv, p);
            if (lane == j) yreg = p;
        }
        ysp[l0 + lane] = yreg;
    }
}

// ---------------------------------------------------------------- k_comb
// ycomb[b,l,:] = (LN_512(sum of 4 permuted directions)*ln_w + ln_b) * silu(z)
__global__ __launch_bounds__(512) void k_comb(const float* __restrict__ ys,
                                              const float* __restrict__ xz,
                                              const float* __restrict__ ln_w,
                                              const float* __restrict__ ln_b,
                                              float* __restrict__ yc) {
    int b = blockIdx.y, l = blockIdx.x, d = threadIdx.x;
    int tpl = ((l & 31) << 5) | (l >> 5);
    const float* yb = ys + (size_t)b * 4 * DIn * Ln;
    float v = yb[(size_t)d * Ln + l]
            + yb[(size_t)(DIn + d) * Ln + tpl]
            + yb[(size_t)(2 * DIn + d) * Ln + (Ln - 1 - l)]
            + yb[(size_t)(3 * DIn + d) * Ln + (Ln - 1 - tpl)];
    float s1 = v, s2 = v * v;
#pragma unroll
    for (int o = 32; o > 0; o >>= 1) { s1 += __shfl_xor(s1, o); s2 += __shfl_xor(s2, o); }
    __shared__ float red[16];
    int wid = threadIdx.x >> 6, lane = threadIdx.x & 63;
    if (lane == 0) { red[wid * 2] = s1; red[wid * 2 + 1] = s2; }
    __syncthreads();
    s1 = 0.f; s2 = 0.f;
#pragma unroll
    for (int w = 0; w < 8; w++) { s1 += red[w * 2]; s2 += red[w * 2 + 1]; }
    float mu  = s1 * (1.f / DIn);
    float var = s2 * (1.f / DIn) - mu * mu;
    float r   = rsqrtf(var + 1e-6f);
    float z   = xz[((size_t)(b << 10) + l) * 1024 + DIn + d];
    yc[((size_t)(b << 10) + l) * DIn + d] = ((v - mu) * r * ln_w[d] + ln_b[d]) * silu_f(z);
}

// ---------------------------------------------------------------- launch
extern "C" void kernel_launch(void* const* d_in, const int* in_sizes, int n_in,
                              void* d_out, int out_size, void* d_ws, size_t ws_size,
                              hipStream_t stream) {
    const float* x      = (const float*)d_in[0];
    const float* c      = (const float*)d_in[1];
    const float* W_ada  = (const float*)d_in[2];
    const float* b_ada  = (const float*)d_in[3];
    const float* W_in   = (const float*)d_in[4];
    const float* b_in   = (const float*)d_in[5];
    const float* conv_w = (const float*)d_in[6];
    const float* conv_b = (const float*)d_in[7];
    const float* W_xp   = (const float*)d_in[8];
    const float* W_dtw  = (const float*)d_in[9];
    const float* dt_b   = (const float*)d_in[10];
    const float* A_log  = (const float*)d_in[11];
    const float* Dp     = (const float*)d_in[12];
    const float* ln_w   = (const float*)d_in[13];
    const float* ln_b   = (const float*)d_in[14];
    const float* W_out  = (const float*)d_in[15];
    const float* b_out  = (const float*)d_in[16];
    const float* W_fc1  = (const float*)d_in[17];
    const float* b_fc1  = (const float*)d_in[18];
    const float* W_fc2  = (const float*)d_in[19];
    const float* b_fc2  = (const float*)d_in[20];
    float* out = (float*)d_out;
    float* ws  = (float*)d_ws;

    // workspace layout (floats)
    float* mod   = ws;                  // 3072
    float* hmod  = mod + 3072;          // 524288
    float* xz    = hmod + 524288;       // 2097152
    float* xic   = xz + 2097152;        // 1048576
    float* xdbl  = xic + 1048576;       // 1179648
    float* dtt   = xdbl + 1179648;      // 4194304
    float* ys    = dtt + 4194304;       // 4194304
    float* ycomb = ys + 4194304;        // 1048576
    float* x1    = ycomb + 1048576;     // 524288
    float* m0    = hmod;                // alias: hmod dead after W_in GEMM
    float* m1    = xz;                  // alias: xz dead after k_comb

    k_mod<<<dim3(6, Bn), 256, 0, stream>>>(c, W_ada, b_ada, mod);
    k_ln_mod<<<dim3(Ln, Bn), 256, 0, stream>>>(x, mod, 0, 256, hmod);
    gemm64<0><<<dim3(16, 32), 256, 0, stream>>>(hmod, W_in, b_in, xz, 1024, 256,
                                                nullptr, nullptr, 0);
    k_conv<<<dim3(4096), 256, 0, stream>>>(xz, conv_w, conv_b, xic);
    gemm_xdbl<<<dim3(3, 32, Bn * Kn), 256, 0, stream>>>(xic, W_xp, xdbl);
    k_dt<<<dim3(16, 8, Bn * Kn), 256, 0, stream>>>(xdbl, W_dtw, dt_b, dtt);
    k_scan<<<dim3(1024), 256, 0, stream>>>(dtt, xdbl, xic, A_log, Dp, ys);
    k_comb<<<dim3(Ln, Bn), 512, 0, stream>>>(ys, xz, ln_w, ln_b, ycomb);
    gemm64<2><<<dim3(4, 32), 256, 0, stream>>>(ycomb, W_out, b_out, x1, 256, 512,
                                               x, mod, 512);
    k_ln_mod<<<dim3(Ln, Bn), 256, 0, stream>>>(x1, mod, 768, 1024, m0);
    gemm64<1><<<dim3(16, 32), 256, 0, stream>>>(m0, W_fc1, b_fc1, m1, 1024, 256,
                                                nullptr, nullptr, 0);
    gemm64<2><<<dim3(4, 32), 256, 0, stream>>>(m1, W_fc2, b_fc2, out, 256, 1024,
                                               x1, mod, 1280);
}